// Round 9
// baseline (271.476 us; speedup 1.0000x reference)
//
#include <hip/hip_runtime.h>

#define BB 128
#define II 512
#define HH 256
#define OO 32
#define FF 16
#define OF 512
#define XTSTR 260     // prep x-transpose LDS stride (ushorts)
#define WVSTR 264     // wvs LDS stride (ushorts)
#define C2STR 520     // c2 LDS stride (ushorts)
#define CXSTR 260     // cx LDS stride (floats)

typedef __attribute__((ext_vector_type(8))) short short8;   // 8 bf16
typedef __attribute__((ext_vector_type(4))) float floatx4;  // MFMA C/D

__device__ __forceinline__ ushort f2bf(float f) {           // RTN-even
  unsigned u = __float_as_uint(f);
  u += 0x7FFFu + ((u >> 16) & 1u);
  return (ushort)(u >> 16);
}
__device__ __forceinline__ float bf2f(ushort u) {
  return __uint_as_float(((unsigned)u) << 16);
}

// ---------- Kernel 1: prep ------------------------------------------------
// grid = 1056, block = 256.
// blocks 0..1023: x -> bf16 x16[b,i,h] + xT16[b,h,i] + xsum partials
// blocks 1024..1055: Wt[j][h] = W[h][j] tile transpose (fp32)
__global__ __launch_bounds__(256) void k_prep(
    const float* __restrict__ x, const float* __restrict__ W,
    ushort* __restrict__ x16, ushort* __restrict__ xT16,
    float* __restrict__ Wt, float* __restrict__ xsum_part) {
  __shared__ __align__(16) unsigned char smem[37376];
  int t = threadIdx.x;
  int blk = blockIdx.x;
  if (blk < 1024) {
    ushort* xt = (ushort*)smem;                  // [64][XTSTR]
    float4* red4 = (float4*)(smem + 33280);      // [4][64]
    int b = blk >> 3, p = blk & 7;
    int c4 = t & 63, grp = t >> 6;
    const float* xg = x + (size_t)blk * 64 * HH;
    ushort* x16g = x16 + (size_t)blk * 64 * HH;
    float4 sum = make_float4(0.f, 0.f, 0.f, 0.f);
#pragma unroll
    for (int j = 0; j < 16; ++j) {
      int row = j * 4 + grp;
      float4 v4 = *(const float4*)(xg + (size_t)row * HH + c4 * 4);
      sum.x += v4.x; sum.y += v4.y; sum.z += v4.z; sum.w += v4.w;
      ushort4 u;
      u.x = f2bf(v4.x); u.y = f2bf(v4.y); u.z = f2bf(v4.z); u.w = f2bf(v4.w);
      *(ushort4*)&xt[row * XTSTR + c4 * 4] = u;
      *(ushort4*)&x16g[(size_t)row * HH + c4 * 4] = u;
    }
    red4[grp * 64 + c4] = sum;
    __syncthreads();
    if (t < 64) {
      float4 s = red4[t], s1 = red4[64 + t], s2 = red4[128 + t], s3 = red4[192 + t];
      s.x += s1.x + s2.x + s3.x; s.y += s1.y + s2.y + s3.y;
      s.z += s1.z + s2.z + s3.z; s.w += s1.w + s2.w + s3.w;
      *(float4*)&xsum_part[(size_t)blk * HH + t * 4] = s;
    }
    // transpose into xT16[b][h][i] (this block fills i-range p*64..p*64+63)
    ushort* xtg = xT16 + (size_t)b * HH * II + (size_t)t * II + p * 64;
#pragma unroll
    for (int ch = 0; ch < 8; ++ch) {
      ushort4 a, bq;
      a.x = xt[(ch * 8 + 0) * XTSTR + t]; a.y = xt[(ch * 8 + 1) * XTSTR + t];
      a.z = xt[(ch * 8 + 2) * XTSTR + t]; a.w = xt[(ch * 8 + 3) * XTSTR + t];
      bq.x = xt[(ch * 8 + 4) * XTSTR + t]; bq.y = xt[(ch * 8 + 5) * XTSTR + t];
      bq.z = xt[(ch * 8 + 6) * XTSTR + t]; bq.w = xt[(ch * 8 + 7) * XTSTR + t];
      *(ushort4*)(xtg + ch * 8) = a;
      *(ushort4*)(xtg + ch * 8 + 4) = bq;
    }
  } else {
    // W transpose: 64x64 fp32 tiles
    float* wls = (float*)smem;                   // [64][68]
    int wblk = blk - 1024;                       // 0..31
    int hr0 = (wblk >> 3) * 64;
    int jc0 = (wblk & 7) * 64;
    int cr = t >> 4, c4 = t & 15;
#pragma unroll
    for (int rr = 0; rr < 4; ++rr) {
      int row = rr * 16 + cr;
      float4 v4 = *(const float4*)&W[(size_t)(hr0 + row) * OF + jc0 + c4 * 4];
      *(float4*)&wls[row * 68 + c4 * 4] = v4;
    }
    __syncthreads();
#pragma unroll
    for (int jj = 0; jj < 4; ++jj) {
      int jl = jj * 16 + cr;
      float4 o4;
      o4.x = wls[(c4 * 4 + 0) * 68 + jl];
      o4.y = wls[(c4 * 4 + 1) * 68 + jl];
      o4.z = wls[(c4 * 4 + 2) * 68 + jl];
      o4.w = wls[(c4 * 4 + 3) * 68 + jl];
      *(float4*)&Wt[(size_t)(jc0 + jl) * HH + hr0 + c4 * 4] = o4;
    }
  }
}

// ---------- Kernel 2: mega — one block per b, everything block-local ------
// grid = 128, block = 1024 (16 waves), 1 block/CU, LDS ~88.5 KB
__global__ __launch_bounds__(1024, 4) void k_mega(
    const ushort* __restrict__ x16, const ushort* __restrict__ xT16,
    const float* __restrict__ Wt, const float* __restrict__ xsum_part,
    float* __restrict__ out) {
  __shared__ ushort wvs[OO * WVSTR];   // 16.9 KB  Wv^T [o][h] bf16
  __shared__ ushort c2[OO * C2STR];    // 33.3 KB  c [o][i] bf16
  __shared__ float cx[OO * CXSTR];     // 33.3 KB  cx [o][h] fp32
  __shared__ float xsum[HH];
  __shared__ float vtmp[OF];
  __shared__ float vres[OF];
  int t = threadIdx.x;
  int b = blockIdx.x;
  int lane = t & 63, w = t >> 6;
  int l16 = lane & 15, quad = lane >> 4;

  // ---- P1: xsum (pre-scaled by 1/32) ----
  if (t < HH) {
    const float* cp = xsum_part + (size_t)b * 8 * HH + t;
    float a = 0.f;
#pragma unroll
    for (int p = 0; p < 8; ++p) a += cp[(size_t)p * HH];
    xsum[t] = a * (1.0f / 32.0f);
  }
  __syncthreads();
  // ---- v-dot from xsum: vtmp[of] = sum_h xsum[h]*Wt[of][h] ----
  {
    float4 xv = *(const float4*)&xsum[lane * 4];
#pragma unroll 4
    for (int j = 0; j < 32; ++j) {
      int of = w * 32 + j;
      float4 wt = *(const float4*)&Wt[(size_t)of * HH + lane * 4];
      float a = xv.x * wt.x + xv.y * wt.y + xv.z * wt.z + xv.w * wt.w;
#pragma unroll
      for (int mask = 1; mask < 64; mask <<= 1) a += __shfl_xor(a, mask);
      if (lane == 0) vtmp[of] = a;
    }
  }
  __syncthreads();
  if (t < OF) {
    float a = vtmp[t];
    float n2 = a * a;
#pragma unroll
    for (int mask = 1; mask < 16; mask <<= 1) n2 += __shfl_xor(n2, mask);
    float sc = sqrtf(n2) / (1.f + n2);
    vres[t] = a * sc;
  }
  __syncthreads();

#pragma unroll 1
  for (int it = 0; it < 2; ++it) {
    // ---- P2: wvs[o][h] = sum_f Wt[o*16+f][h] * vres[o*16+f] ----
#pragma unroll
    for (int oo = 0; oo < 2; ++oo) {
      int o = w * 2 + oo;
      float4 acc = make_float4(0.f, 0.f, 0.f, 0.f);
#pragma unroll
      for (int f = 0; f < FF; ++f) {
        float vv = vres[o * FF + f];
        float4 wt = *(const float4*)&Wt[(size_t)(o * FF + f) * HH + lane * 4];
        acc.x += vv * wt.x; acc.y += vv * wt.y;
        acc.z += vv * wt.z; acc.w += vv * wt.w;
      }
      ushort4 u;
      u.x = f2bf(acc.x); u.y = f2bf(acc.y); u.z = f2bf(acc.z); u.w = f2bf(acc.w);
      *(ushort4*)&wvs[o * WVSTR + lane * 4] = u;
    }
    __syncthreads();
    // ---- P3: GEMM1 D[i][o] (M=512,N=32,K=256) + softmax -> c2[o][i] ----
    {
      floatx4 acc[2][2];
#pragma unroll
      for (int mt = 0; mt < 2; ++mt)
#pragma unroll
        for (int nt = 0; nt < 2; ++nt)
          acc[mt][nt] = (floatx4){0.f, 0.f, 0.f, 0.f};
#pragma unroll
      for (int ks = 0; ks < 8; ++ks) {
        short8 b0 = *(const short8*)&wvs[l16 * WVSTR + ks * 32 + quad * 8];
        short8 b1 = *(const short8*)&wvs[(16 + l16) * WVSTR + ks * 32 + quad * 8];
#pragma unroll
        for (int mt = 0; mt < 2; ++mt) {
          short8 af = *(const short8*)(x16 + ((size_t)b * II + (w * 2 + mt) * 16 + l16) * HH + ks * 32 + quad * 8);
          acc[mt][0] = __builtin_amdgcn_mfma_f32_16x16x32_bf16(af, b0, acc[mt][0], 0, 0, 0);
          acc[mt][1] = __builtin_amdgcn_mfma_f32_16x16x32_bf16(af, b1, acc[mt][1], 0, 0, 0);
        }
      }
#pragma unroll
      for (int mt = 0; mt < 2; ++mt)
#pragma unroll
        for (int r = 0; r < 4; ++r) {
          float a0 = acc[mt][0][r], a1 = acc[mt][1][r];
          float m = fmaxf(a0, a1);
#pragma unroll
          for (int mask = 1; mask < 16; mask <<= 1) m = fmaxf(m, __shfl_xor(m, mask));
          float e0 = __expf(a0 - m), e1 = __expf(a1 - m);
          float s = e0 + e1;
#pragma unroll
          for (int mask = 1; mask < 16; mask <<= 1) s += __shfl_xor(s, mask);
          float inv = 1.f / s;
          int ig = (w * 2 + mt) * 16 + quad * 4 + r;
          c2[l16 * C2STR + ig] = f2bf(e0 * inv);
          c2[(16 + l16) * C2STR + ig] = f2bf(e1 * inv);
        }
    }
    __syncthreads();
    // ---- P4: GEMM2 D[o][h] (M=32,N=256,K=512) -> cx ----
    {
      floatx4 d0 = {0.f, 0.f, 0.f, 0.f}, d1 = {0.f, 0.f, 0.f, 0.f};
#pragma unroll
      for (int ks = 0; ks < 16; ++ks) {
        short8 bf = *(const short8*)(xT16 + ((size_t)b * HH + w * 16 + l16) * II + ks * 32 + quad * 8);
        short8 a0 = *(const short8*)&c2[l16 * C2STR + ks * 32 + quad * 8];
        short8 a1 = *(const short8*)&c2[(16 + l16) * C2STR + ks * 32 + quad * 8];
        d0 = __builtin_amdgcn_mfma_f32_16x16x32_bf16(a0, bf, d0, 0, 0, 0);
        d1 = __builtin_amdgcn_mfma_f32_16x16x32_bf16(a1, bf, d1, 0, 0, 0);
      }
#pragma unroll
      for (int r = 0; r < 4; ++r) {
        cx[(quad * 4 + r) * CXSTR + w * 16 + l16] = d0[r];
        cx[(16 + quad * 4 + r) * CXSTR + w * 16 + l16] = d1[r];
      }
    }
    __syncthreads();
    // ---- P5: v-dot from cx: vtmp[of] = sum_h cx[of>>4][h]*Wt[of][h] ----
#pragma unroll 4
    for (int j = 0; j < 32; ++j) {
      int of = w * 32 + j;
      int o = of >> 4;
      float4 xv = *(const float4*)&cx[o * CXSTR + lane * 4];
      float4 wt = *(const float4*)&Wt[(size_t)of * HH + lane * 4];
      float a = xv.x * wt.x + xv.y * wt.y + xv.z * wt.z + xv.w * wt.w;
#pragma unroll
      for (int mask = 1; mask < 64; mask <<= 1) a += __shfl_xor(a, mask);
      if (lane == 0) vtmp[of] = a;
    }
    __syncthreads();
    if (t < OF) {
      float a = vtmp[t];
      float n2 = a * a;
#pragma unroll
      for (int mask = 1; mask < 16; mask <<= 1) n2 += __shfl_xor(n2, mask);
      float sc = sqrtf(n2) / (1.f + n2);
      float res = a * sc;
      if (it == 1) out[(size_t)b * OF + t] = res;
      else vres[t] = res;
    }
    __syncthreads();
  }
}

extern "C" void kernel_launch(void* const* d_in, const int* in_sizes, int n_in,
                              void* d_out, int out_size, void* d_ws, size_t ws_size,
                              hipStream_t stream) {
  const float* x = (const float*)d_in[0];  // [128,512,256] fp32
  const float* W = (const float*)d_in[1];  // [1,256,512]   fp32
  float* out = (float*)d_out;              // [128,32,16]   fp32
  float* ws = (float*)d_ws;
  // workspace (float offsets), total ~65.5 MiB
  float*  xsum_part = ws;                          // 262144 floats
  float*  Wt    = ws + 262144;                     // 131072 floats
  ushort* x16   = (ushort*)(ws + 393216);          // 16,777,216 ushorts
  ushort* xT16  = (ushort*)(ws + 8781824);         // 16,777,216 ushorts

  k_prep<<<1056, 256, 0, stream>>>(x, W, x16, xT16, Wt, xsum_part);
  k_mega<<<BB, 1024, 0, stream>>>(x16, xT16, Wt, xsum_part, out);
}

// Round 10
// 251.702 us; speedup vs baseline: 1.0786x; 1.0786x over previous
//
#include <hip/hip_runtime.h>

#define BB 128
#define II 512
#define HH 256
#define OO 32
#define FF 16
#define OF 512
#define XTSTR 260     // prep x-transpose LDS stride (ushorts)
#define WVSTR 264     // wvs LDS stride (ushorts)
#define C2STR 520     // c2 LDS stride (ushorts)
#define CXSTR 260     // cx LDS stride (floats)

typedef __attribute__((ext_vector_type(8))) short short8;   // 8 bf16
typedef __attribute__((ext_vector_type(4))) float floatx4;  // MFMA C/D

__device__ __forceinline__ ushort f2bf(float f) {           // RTN-even
  unsigned u = __float_as_uint(f);
  u += 0x7FFFu + ((u >> 16) & 1u);
  return (ushort)(u >> 16);
}
__device__ __forceinline__ float bf2f(ushort u) {
  return __uint_as_float(((unsigned)u) << 16);
}

// ---------- Kernel 1: prep (unchanged from R9) ----------------------------
// grid = 1056, block = 256.
// blocks 0..1023: x -> bf16 x16[b,i,h] + xT16[b,h,i] + xsum partials
// blocks 1024..1055: Wt[j][h] = W[h][j] tile transpose (fp32)
__global__ __launch_bounds__(256) void k_prep(
    const float* __restrict__ x, const float* __restrict__ W,
    ushort* __restrict__ x16, ushort* __restrict__ xT16,
    float* __restrict__ Wt, float* __restrict__ xsum_part) {
  __shared__ __align__(16) unsigned char smem[37376];
  int t = threadIdx.x;
  int blk = blockIdx.x;
  if (blk < 1024) {
    ushort* xt = (ushort*)smem;                  // [64][XTSTR]
    float4* red4 = (float4*)(smem + 33280);      // [4][64]
    int b = blk >> 3, p = blk & 7;
    int c4 = t & 63, grp = t >> 6;
    const float* xg = x + (size_t)blk * 64 * HH;
    ushort* x16g = x16 + (size_t)blk * 64 * HH;
    float4 sum = make_float4(0.f, 0.f, 0.f, 0.f);
#pragma unroll
    for (int j = 0; j < 16; ++j) {
      int row = j * 4 + grp;
      float4 v4 = *(const float4*)(xg + (size_t)row * HH + c4 * 4);
      sum.x += v4.x; sum.y += v4.y; sum.z += v4.z; sum.w += v4.w;
      ushort4 u;
      u.x = f2bf(v4.x); u.y = f2bf(v4.y); u.z = f2bf(v4.z); u.w = f2bf(v4.w);
      *(ushort4*)&xt[row * XTSTR + c4 * 4] = u;
      *(ushort4*)&x16g[(size_t)row * HH + c4 * 4] = u;
    }
    red4[grp * 64 + c4] = sum;
    __syncthreads();
    if (t < 64) {
      float4 s = red4[t], s1 = red4[64 + t], s2 = red4[128 + t], s3 = red4[192 + t];
      s.x += s1.x + s2.x + s3.x; s.y += s1.y + s2.y + s3.y;
      s.z += s1.z + s2.z + s3.z; s.w += s1.w + s2.w + s3.w;
      *(float4*)&xsum_part[(size_t)blk * HH + t * 4] = s;
    }
    ushort* xtg = xT16 + (size_t)b * HH * II + (size_t)t * II + p * 64;
#pragma unroll
    for (int ch = 0; ch < 8; ++ch) {
      ushort4 a, bq;
      a.x = xt[(ch * 8 + 0) * XTSTR + t]; a.y = xt[(ch * 8 + 1) * XTSTR + t];
      a.z = xt[(ch * 8 + 2) * XTSTR + t]; a.w = xt[(ch * 8 + 3) * XTSTR + t];
      bq.x = xt[(ch * 8 + 4) * XTSTR + t]; bq.y = xt[(ch * 8 + 5) * XTSTR + t];
      bq.z = xt[(ch * 8 + 6) * XTSTR + t]; bq.w = xt[(ch * 8 + 7) * XTSTR + t];
      *(ushort4*)(xtg + ch * 8) = a;
      *(ushort4*)(xtg + ch * 8 + 4) = bq;
    }
  } else {
    float* wls = (float*)smem;                   // [64][68]
    int wblk = blk - 1024;                       // 0..31
    int hr0 = (wblk >> 3) * 64;
    int jc0 = (wblk & 7) * 64;
    int cr = t >> 4, c4 = t & 15;
#pragma unroll
    for (int rr = 0; rr < 4; ++rr) {
      int row = rr * 16 + cr;
      float4 v4 = *(const float4*)&W[(size_t)(hr0 + row) * OF + jc0 + c4 * 4];
      *(float4*)&wls[row * 68 + c4 * 4] = v4;
    }
    __syncthreads();
#pragma unroll
    for (int jj = 0; jj < 4; ++jj) {
      int jl = jj * 16 + cr;
      float4 o4;
      o4.x = wls[(c4 * 4 + 0) * 68 + jl];
      o4.y = wls[(c4 * 4 + 1) * 68 + jl];
      o4.z = wls[(c4 * 4 + 2) * 68 + jl];
      o4.w = wls[(c4 * 4 + 3) * 68 + jl];
      *(float4*)&Wt[(size_t)(jc0 + jl) * HH + hr0 + c4 * 4] = o4;
    }
  }
}

// ---------- Kernel 2: mega — one block per b, 512 threads (8 waves) -------
// grid = 128, 1 block/CU (LDS 88.5 KB). 8 waves -> VGPR budget 256: no spill.
__global__ __launch_bounds__(512) void k_mega(
    const ushort* __restrict__ x16, const ushort* __restrict__ xT16,
    const float* __restrict__ Wt, const float* __restrict__ xsum_part,
    float* __restrict__ out) {
  __shared__ ushort wvs[OO * WVSTR];   // 16.9 KB  Wv^T [o][h] bf16
  __shared__ ushort c2[OO * C2STR];    // 33.3 KB  c [o][i] bf16
  __shared__ float cx[OO * CXSTR];     // 33.3 KB  cx [o][h] fp32
  __shared__ float xsum[HH];
  __shared__ float vtmp[OF];
  __shared__ float vres[OF];
  int t = threadIdx.x;
  int b = blockIdx.x;
  int lane = t & 63, w = t >> 6;       // 8 waves
  int l16 = lane & 15, quad = lane >> 4;

  // ---- P1: xsum (pre-scaled by 1/32) ----
  if (t < HH) {
    const float* cp = xsum_part + (size_t)b * 8 * HH + t;
    float a = 0.f;
#pragma unroll
    for (int p = 0; p < 8; ++p) a += cp[(size_t)p * HH];
    xsum[t] = a * (1.0f / 32.0f);
  }
  __syncthreads();
  // ---- v-dot from xsum: vtmp[of] = sum_h xsum[h]*Wt[of][h] ----
  {
    float4 xv = *(const float4*)&xsum[lane * 4];
#pragma unroll 2
    for (int j = 0; j < 32; ++j) {
      int of0 = w * 64 + j, of1 = of0 + 32;
      float4 w0 = *(const float4*)&Wt[(size_t)of0 * HH + lane * 4];
      float4 w1 = *(const float4*)&Wt[(size_t)of1 * HH + lane * 4];
      float a0 = xv.x * w0.x + xv.y * w0.y + xv.z * w0.z + xv.w * w0.w;
      float a1 = xv.x * w1.x + xv.y * w1.y + xv.z * w1.z + xv.w * w1.w;
#pragma unroll
      for (int mask = 1; mask < 64; mask <<= 1) {
        a0 += __shfl_xor(a0, mask);
        a1 += __shfl_xor(a1, mask);
      }
      if (lane == 0) { vtmp[of0] = a0; vtmp[of1] = a1; }
    }
  }
  __syncthreads();
  if (t < OF) {
    float a = vtmp[t];
    float n2 = a * a;
#pragma unroll
    for (int mask = 1; mask < 16; mask <<= 1) n2 += __shfl_xor(n2, mask);
    float sc = sqrtf(n2) / (1.f + n2);
    vres[t] = a * sc;
  }
  __syncthreads();

#pragma unroll 1
  for (int it = 0; it < 2; ++it) {
    // ---- P2: wvs[o][h] = sum_f Wt[o*16+f][h] * vres[o*16+f] ----
#pragma unroll
    for (int oo = 0; oo < 4; ++oo) {
      int o = w * 4 + oo;
      float4 acc = make_float4(0.f, 0.f, 0.f, 0.f);
#pragma unroll
      for (int f = 0; f < FF; ++f) {
        float vv = vres[o * FF + f];
        float4 wt = *(const float4*)&Wt[(size_t)(o * FF + f) * HH + lane * 4];
        acc.x += vv * wt.x; acc.y += vv * wt.y;
        acc.z += vv * wt.z; acc.w += vv * wt.w;
      }
      ushort4 u;
      u.x = f2bf(acc.x); u.y = f2bf(acc.y); u.z = f2bf(acc.z); u.w = f2bf(acc.w);
      *(ushort4*)&wvs[o * WVSTR + lane * 4] = u;
    }
    __syncthreads();
    // ---- P3: GEMM1 D[i][o] (M=512,N=32,K=256) + softmax -> c2[o][i] ----
    {
      floatx4 acc[4][2];
#pragma unroll
      for (int mt = 0; mt < 4; ++mt)
#pragma unroll
        for (int nt = 0; nt < 2; ++nt)
          acc[mt][nt] = (floatx4){0.f, 0.f, 0.f, 0.f};
#pragma unroll
      for (int ks = 0; ks < 8; ++ks) {
        short8 b0 = *(const short8*)&wvs[l16 * WVSTR + ks * 32 + quad * 8];
        short8 b1 = *(const short8*)&wvs[(16 + l16) * WVSTR + ks * 32 + quad * 8];
#pragma unroll
        for (int mt = 0; mt < 4; ++mt) {
          short8 af = *(const short8*)(x16 + ((size_t)b * II + (w * 4 + mt) * 16 + l16) * HH + ks * 32 + quad * 8);
          acc[mt][0] = __builtin_amdgcn_mfma_f32_16x16x32_bf16(af, b0, acc[mt][0], 0, 0, 0);
          acc[mt][1] = __builtin_amdgcn_mfma_f32_16x16x32_bf16(af, b1, acc[mt][1], 0, 0, 0);
        }
      }
#pragma unroll
      for (int mt = 0; mt < 4; ++mt)
#pragma unroll
        for (int r = 0; r < 4; ++r) {
          float a0 = acc[mt][0][r], a1 = acc[mt][1][r];
          float m = fmaxf(a0, a1);
#pragma unroll
          for (int mask = 1; mask < 16; mask <<= 1) m = fmaxf(m, __shfl_xor(m, mask));
          float e0 = __expf(a0 - m), e1 = __expf(a1 - m);
          float s = e0 + e1;
#pragma unroll
          for (int mask = 1; mask < 16; mask <<= 1) s += __shfl_xor(s, mask);
          float inv = 1.f / s;
          int ig = (w * 4 + mt) * 16 + quad * 4 + r;
          c2[l16 * C2STR + ig] = f2bf(e0 * inv);
          c2[(16 + l16) * C2STR + ig] = f2bf(e1 * inv);
        }
    }
    __syncthreads();
    // ---- P4: GEMM2 D[o][h] (M=32,N=256,K=512) -> cx ----
#pragma unroll
    for (int ntl = 0; ntl < 2; ++ntl) {
      int nt = w * 2 + ntl;              // h-tile
      floatx4 d0 = {0.f, 0.f, 0.f, 0.f}, d1 = {0.f, 0.f, 0.f, 0.f};
#pragma unroll
      for (int ks = 0; ks < 16; ++ks) {
        short8 bf = *(const short8*)(xT16 + ((size_t)b * HH + nt * 16 + l16) * II + ks * 32 + quad * 8);
        short8 a0 = *(const short8*)&c2[l16 * C2STR + ks * 32 + quad * 8];
        short8 a1 = *(const short8*)&c2[(16 + l16) * C2STR + ks * 32 + quad * 8];
        d0 = __builtin_amdgcn_mfma_f32_16x16x32_bf16(a0, bf, d0, 0, 0, 0);
        d1 = __builtin_amdgcn_mfma_f32_16x16x32_bf16(a1, bf, d1, 0, 0, 0);
      }
#pragma unroll
      for (int r = 0; r < 4; ++r) {
        cx[(quad * 4 + r) * CXSTR + nt * 16 + l16] = d0[r];
        cx[(16 + quad * 4 + r) * CXSTR + nt * 16 + l16] = d1[r];
      }
    }
    __syncthreads();
    // ---- P5: v-dot from cx: vtmp[of] = sum_h cx[of>>4][h]*Wt[of][h] ----
#pragma unroll 2
    for (int j = 0; j < 32; ++j) {
      int of0 = w * 64 + j, of1 = of0 + 32;
      float4 x0 = *(const float4*)&cx[(of0 >> 4) * CXSTR + lane * 4];
      float4 x1 = *(const float4*)&cx[(of1 >> 4) * CXSTR + lane * 4];
      float4 w0 = *(const float4*)&Wt[(size_t)of0 * HH + lane * 4];
      float4 w1 = *(const float4*)&Wt[(size_t)of1 * HH + lane * 4];
      float a0 = x0.x * w0.x + x0.y * w0.y + x0.z * w0.z + x0.w * w0.w;
      float a1 = x1.x * w1.x + x1.y * w1.y + x1.z * w1.z + x1.w * w1.w;
#pragma unroll
      for (int mask = 1; mask < 64; mask <<= 1) {
        a0 += __shfl_xor(a0, mask);
        a1 += __shfl_xor(a1, mask);
      }
      if (lane == 0) { vtmp[of0] = a0; vtmp[of1] = a1; }
    }
    __syncthreads();
    if (t < OF) {
      float a = vtmp[t];
      float n2 = a * a;
#pragma unroll
      for (int mask = 1; mask < 16; mask <<= 1) n2 += __shfl_xor(n2, mask);
      float sc = sqrtf(n2) / (1.f + n2);
      float res = a * sc;
      if (it == 1) out[(size_t)b * OF + t] = res;
      else vres[t] = res;
    }
    __syncthreads();
  }
}

extern "C" void kernel_launch(void* const* d_in, const int* in_sizes, int n_in,
                              void* d_out, int out_size, void* d_ws, size_t ws_size,
                              hipStream_t stream) {
  const float* x = (const float*)d_in[0];  // [128,512,256] fp32
  const float* W = (const float*)d_in[1];  // [1,256,512]   fp32
  float* out = (float*)d_out;              // [128,32,16]   fp32
  float* ws = (float*)d_ws;
  // workspace (float offsets), total ~65.5 MiB
  float*  xsum_part = ws;                          // 262144 floats
  float*  Wt    = ws + 262144;                     // 131072 floats
  ushort* x16   = (ushort*)(ws + 393216);          // 16,777,216 ushorts
  ushort* xT16  = (ushort*)(ws + 8781824);         // 16,777,216 ushorts

  k_prep<<<1056, 256, 0, stream>>>(x, W, x16, xT16, Wt, xsum_part);
  k_mega<<<BB, 512, 0, stream>>>(x16, xT16, Wt, xsum_part, out);
}